// Round 8
// baseline (795.195 us; speedup 1.0000x reference)
//
#include <hip/hip_runtime.h>
#include <math.h>

#define NB 32
#define NL 512
#define ND 384
#define NH 6
#define NCP 52
#define NC 50
#define NBH (NB * NH)   // 192 head-batches

// XOR swizzle for [row][64] f32 LDS tiles: 16B-chunk permute keyed on row>>3 so the
// 16 rows a wave reads at stride-64 land on 8 distinct chunk slots (2-way = free).
__device__ __forceinline__ int swz(int row, int k) {
    return k ^ (((row >> 3) & 7) << 2);
}

// XCD-chunked decode, grid 1536 (B pass): 8 XCDs x 192; consecutive sid share (b,h).
__device__ __forceinline__ void decode_blk(int orig, int& bh, int& i0) {
    int sid = (orig & 7) * 192 + (orig >> 3);
    i0 = (sid & 7) << 6;
    bh = sid >> 3;
}

// XCD-chunked decode, grid 768 (A/C passes, 128-row tiles).
__device__ __forceinline__ void decode_blk4(int orig, int& bh, int& i0) {
    int sid = (orig & 7) * 96 + (orig >> 3);
    i0 = (sid & 3) << 7;
    bh = sid >> 2;
}

// stage a 64x64 f32 tile (row-major, ld=64) into swizzled LDS; 256 threads
__device__ __forceinline__ void stage_tile(const float* __restrict__ src, float* dst, int t) {
#pragma unroll
    for (int it = 0; it < 4; ++it) {
        int f4i = t + (it << 8);
        int row = f4i >> 4, kc = (f4i & 15) << 2;
        float4 v = *(const float4*)(src + (size_t)row * 64 + kc);
        *(float4*)(dst + row * 64 + swz(row, kc)) = v;
    }
}

// stage a 128x64 f32 tile into swizzled LDS; 256 threads
__device__ __forceinline__ void stage128(const float* __restrict__ src, float* dst, int t) {
#pragma unroll
    for (int it = 0; it < 8; ++it) {
        int f4i = t + (it << 8);
        int row = f4i >> 4, kc = (f4i & 15) << 2;
        float4 v = *(const float4*)(src + (size_t)row * 64 + kc);
        *(float4*)(dst + row * 64 + swz(row, kc)) = v;
    }
}

// 4x4 per-thread distance tile (64x64 block tile) -- used by pass B (needs Es).
__device__ __forceinline__ void dist_tile(const float* As, const float* Bs,
                                          const float* q2i, const float* q2j,
                                          int tx, int ty, float co[4][4]) {
    float acc[4][4] = {};
    for (int kc = 0; kc < 64; kc += 4) {
        float4 a[4], bb[4];
#pragma unroll
        for (int r = 0; r < 4; ++r)
            a[r] = *(const float4*)(As + (ty * 4 + r) * 64 + swz(ty * 4 + r, kc));
#pragma unroll
        for (int c = 0; c < 4; ++c)
            bb[c] = *(const float4*)(Bs + (tx * 4 + c) * 64 + swz(tx * 4 + c, kc));
#pragma unroll
        for (int r = 0; r < 4; ++r)
#pragma unroll
            for (int c = 0; c < 4; ++c)
                acc[r][c] += a[r].x * bb[c].x + a[r].y * bb[c].y + a[r].z * bb[c].z + a[r].w * bb[c].w;
    }
#pragma unroll
    for (int r = 0; r < 4; ++r)
#pragma unroll
        for (int c = 0; c < 4; ++c) {
            float d = q2i[ty * 4 + r] + q2j[tx * 4 + c] - 2.f * acc[r][c];
            co[r][c] = sqrtf(fmaxf(d, 0.f) + 1e-12f);
        }
}

// 8x8 per-thread dot-product accumulator (128x128 block tile): 16 FMA per LDS read.
__device__ __forceinline__ void dist8_acc(const float* As, const float* Bs,
                                          int tx, int ty, float acc[8][8]) {
#pragma unroll
    for (int r = 0; r < 8; ++r)
#pragma unroll
        for (int c = 0; c < 8; ++c) acc[r][c] = 0.f;
    for (int kc = 0; kc < 64; kc += 4) {
        float4 a[8], bb[8];
#pragma unroll
        for (int r = 0; r < 8; ++r)
            a[r] = *(const float4*)(As + (ty * 8 + r) * 64 + swz(ty * 8 + r, kc));
#pragma unroll
        for (int c = 0; c < 8; ++c)
            bb[c] = *(const float4*)(Bs + (tx * 8 + c) * 64 + swz(tx * 8 + c, kc));
#pragma unroll
        for (int r = 0; r < 8; ++r)
#pragma unroll
            for (int c = 0; c < 8; ++c)
                acc[r][c] += a[r].x * bb[c].x + a[r].y * bb[c].y + a[r].z * bb[c].z + a[r].w * bb[c].w;
    }
}

// ---------------- zero accumulators ----------------
__global__ void zero_kernel(float4* zb) {
    int idx = blockIdx.x * 256 + threadIdx.x;
    float4 z; z.x = 0.f; z.y = 0.f; z.z = 0.f; z.w = 0.f;
    for (int i = idx; i < 25000; i += 64 * 256) zb[i] = z;
}

// ---------------- embedding + tfidf weight + q2 ----------------
__global__ __launch_bounds__(384) void embed_kernel(
    const int* __restrict__ tids, const int* __restrict__ TFs, const int* __restrict__ DFs,
    const float* __restrict__ emb, float* __restrict__ hw, float* __restrict__ q2) {
    int t = threadIdx.x;
    int bl = blockIdx.x;               // 0..B*L-1
    int b = bl >> 9, l = bl & 511;
    int tid = tids[bl];
    float tf = log1pf(fminf((float)TFs[bl], 20.f));
    float idf = 1.f / logf((float)DFs[bl] + 2.f);
    float wt = tf * idf;
    float hv = emb[(size_t)tid * ND + t] * wt;
    int hh = t >> 6, dd = t & 63;
    hw[((size_t)(b * NH + hh) * NL + l) * 64 + dd] = hv;
    float q = hv * hv;
    for (int off = 1; off < 64; off <<= 1) q += __shfl_xor(q, off);
    if (dd == 0) q2[(b * NH + hh) * NL + l] = q;
}

// ---------------- pass A: recompute distances -> BN stats (128x128 tiles, 8x8/thread) ----
__global__ __launch_bounds__(256, 2) void distA_kernel(
    const float* __restrict__ hw, const float* __restrict__ q2g, double* __restrict__ stats) {
    __shared__ float As[8192], Bs[8192];
    __shared__ float q2i[128], q2j[128];
    __shared__ float red[8];
    int t = threadIdx.x;
    int bh, i0; decode_blk4(blockIdx.x, bh, i0);
    const float* hb = hw + (size_t)bh * (NL * 64);
    const float* q2b = q2g + bh * NL;
    stage128(hb + (size_t)i0 * 64, As, t);
    if (t < 128) q2i[t] = q2b[i0 + t];
    int tx = t & 15, ty = t >> 4;
    float lsum = 0.f, lss = 0.f;
    for (int jt = 0; jt < 4; ++jt) {
        __syncthreads();
        stage128(hb + (size_t)(jt << 7) * 64, Bs, t);
        if (t < 128) q2j[t] = q2b[(jt << 7) + t];
        __syncthreads();
        float acc[8][8];
        dist8_acc(As, Bs, tx, ty, acc);
#pragma unroll
        for (int r = 0; r < 8; ++r) {
            float q2iv = q2i[ty * 8 + r];
#pragma unroll
            for (int c = 0; c < 8; ++c) {
                float d = q2iv + q2j[tx * 8 + c] - 2.f * acc[r][c];
                float cv = sqrtf(fmaxf(d, 0.f) + 1e-12f);
                lsum += cv;
                lss += cv * cv;
            }
        }
    }
    for (int off = 1; off < 64; off <<= 1) {
        lsum += __shfl_xor(lsum, off);
        lss += __shfl_xor(lss, off);
    }
    __syncthreads();
    if ((t & 63) == 0) { red[(t >> 6) * 2] = lsum; red[(t >> 6) * 2 + 1] = lss; }
    __syncthreads();
    if (t == 0) {
        float s = 0.f, ss = 0.f;
        for (int w = 0; w < 4; ++w) { s += red[w * 2]; ss += red[w * 2 + 1]; }
        int h = bh % NH;
        atomicAdd(&stats[h * 2], (double)s);
        atomicAdd(&stats[h * 2 + 1], (double)ss);
    }
}

// ---------------- finalize BN affine for all heads ----------------
__global__ void fin_kernel(const double* __restrict__ stats, const float* __restrict__ gamma,
                           const float* __restrict__ beta, float* __restrict__ bnab) {
    int h = threadIdx.x;
    if (h < NH) {
        double n = (double)NB * NL * NL;
        double mu = stats[h * 2] / n;
        double var = stats[h * 2 + 1] / n - mu * mu;
        double inv = 1.0 / sqrt(var + 1e-5);
        double a = (double)gamma[h] * inv;
        bnab[h * 2] = (float)a;
        bnab[h * 2 + 1] = (float)((double)beta[h] - mu * a);
    }
}

// ---------------- pass B: dist + exp -> PV + row sums (64x64 tiles, no colsum) --------
__global__ __launch_bounds__(256, 3) void distPV_kernel(
    const float* __restrict__ hw, const float* __restrict__ q2g, const int* __restrict__ tids,
    const float* __restrict__ bnab, float* __restrict__ Vcat, float* __restrict__ rowinv) {
    __shared__ float As[4096], Bs[4096], Es[4096];
    __shared__ float q2i[64], q2j[64], rl[64];
    __shared__ int padi[64], padj[64];
    int t = threadIdx.x;
    int bh, i0; decode_blk(blockIdx.x, bh, i0);
    int b = bh / NH, h = bh % NH;
    float a = bnab[h * 2], bc = bnab[h * 2 + 1];
    const float* hb = hw + (size_t)bh * (NL * 64);
    const float* q2b = q2g + bh * NL;
    stage_tile(hb + (size_t)i0 * 64, As, t);
    if (t < 64) {
        q2i[t] = q2b[i0 + t];
        padi[t] = (tids[(b << 9) + i0 + t] != 0) ? 1 : 0;
    }
    int tx = t & 15, ty = t >> 4;
    float U[4][4] = {};
    float lac[4] = {0.f, 0.f, 0.f, 0.f};
    for (int jt = 0; jt < 8; ++jt) {
        __syncthreads();               // prior Es/Bs consumers done
        stage_tile(hb + (size_t)(jt << 6) * 64, Bs, t);
        if (t < 64) {
            q2j[t] = q2b[(jt << 6) + t];
            padj[t] = (tids[(b << 9) + (jt << 6) + t] != 0) ? 1 : 0;
        }
        __syncthreads();
        float co[4][4];
        dist_tile(As, Bs, q2i, q2j, tx, ty, co);
        bool pj0 = padj[tx * 4 + 0] != 0, pj1 = padj[tx * 4 + 1] != 0;
        bool pj2 = padj[tx * 4 + 2] != 0, pj3 = padj[tx * 4 + 3] != 0;
#pragma unroll
        for (int r = 0; r < 4; ++r) {
            int i = ty * 4 + r;
            bool pi = padi[i] != 0;
            float4 e;
            e.x = __expf((pi && pj0) ? fmaf(a, co[r][0], bc) : 0.f);
            e.y = __expf((pi && pj1) ? fmaf(a, co[r][1], bc) : 0.f);
            e.z = __expf((pi && pj2) ? fmaf(a, co[r][2], bc) : 0.f);
            e.w = __expf((pi && pj3) ? fmaf(a, co[r][3], bc) : 0.f);
            lac[r] += e.x + e.y + e.z + e.w;
            *(float4*)(Es + i * 64 + swz(i, tx << 2)) = e;
        }
        __syncthreads();               // Es ready
        for (int jc = 0; jc < 64; jc += 4) {
            float4 pa[4], vb[4];
#pragma unroll
            for (int r = 0; r < 4; ++r)
                pa[r] = *(const float4*)(Es + (ty * 4 + r) * 64 + swz(ty * 4 + r, jc));
#pragma unroll
            for (int u = 0; u < 4; ++u)
                vb[u] = *(const float4*)(Bs + (jc + u) * 64 + swz(jc + u, tx << 2));
#pragma unroll
            for (int r = 0; r < 4; ++r) {
                U[r][0] += pa[r].x * vb[0].x + pa[r].y * vb[1].x + pa[r].z * vb[2].x + pa[r].w * vb[3].x;
                U[r][1] += pa[r].x * vb[0].y + pa[r].y * vb[1].y + pa[r].z * vb[2].y + pa[r].w * vb[3].y;
                U[r][2] += pa[r].x * vb[0].z + pa[r].y * vb[1].z + pa[r].z * vb[2].z + pa[r].w * vb[3].z;
                U[r][3] += pa[r].x * vb[0].w + pa[r].y * vb[1].w + pa[r].z * vb[2].w + pa[r].w * vb[3].w;
            }
        }
    }
    // row sums over j: reduce across tx lanes (bits 0..3)
#pragma unroll
    for (int r = 0; r < 4; ++r) {
        float s = lac[r];
        s += __shfl_xor(s, 1); s += __shfl_xor(s, 2);
        s += __shfl_xor(s, 4); s += __shfl_xor(s, 8);
        if (tx == 0) {
            float inv = 1.f / s;
            rl[ty * 4 + r] = inv;
            rowinv[(size_t)bh * NL + i0 + ty * 4 + r] = inv;
        }
    }
    __syncthreads();
#pragma unroll
    for (int r = 0; r < 4; ++r) {
        int i = ty * 4 + r;
        float rr = rl[i];
        float4 o;
        o.x = U[r][0] * rr; o.y = U[r][1] * rr; o.z = U[r][2] * rr; o.w = U[r][3] * rr;
        *(float4*)(Vcat + ((size_t)(b << 9) + i0 + i) * ND + h * 64 + (tx << 2)) = o;
    }
}

// ---------------- pass C: dist + exp*(1/l) -> colsum (128x128 tiles, 8x8/thread) ------
__global__ __launch_bounds__(256, 2) void colsumC_kernel(
    const float* __restrict__ hw, const float* __restrict__ q2g, const int* __restrict__ tids,
    const float* __restrict__ bnab, const float* __restrict__ rowinv, float* __restrict__ colsum) {
    __shared__ float As[8192], Bs[8192];
    __shared__ float q2i[128], q2j[128], rl[128];
    __shared__ int padi[128], padj[128];
    __shared__ float csw[4][512];
    int t = threadIdx.x;
    int bh, i0; decode_blk4(blockIdx.x, bh, i0);
    int b = bh / NH, h = bh % NH;
    float a = bnab[h * 2], bc = bnab[h * 2 + 1];
    const float* hb = hw + (size_t)bh * (NL * 64);
    const float* q2b = q2g + bh * NL;
    stage128(hb + (size_t)i0 * 64, As, t);
    if (t < 128) {
        q2i[t] = q2b[i0 + t];
        padi[t] = (tids[(b << 9) + i0 + t] != 0) ? 1 : 0;
        rl[t] = rowinv[(size_t)bh * NL + i0 + t];
    }
    for (int k = t; k < 2048; k += 256) ((float*)csw)[k] = 0.f;
    int tx = t & 15, ty = t >> 4, wv = t >> 6;
    for (int jt = 0; jt < 4; ++jt) {
        __syncthreads();
        stage128(hb + (size_t)(jt << 7) * 64, Bs, t);
        if (t < 128) {
            q2j[t] = q2b[(jt << 7) + t];
            padj[t] = (tids[(b << 9) + (jt << 7) + t] != 0) ? 1 : 0;
        }
        __syncthreads();
        float acc[8][8];
        dist8_acc(As, Bs, tx, ty, acc);
        float cp[8] = {};
#pragma unroll
        for (int r = 0; r < 8; ++r) {
            int i = ty * 8 + r;
            bool pi = padi[i] != 0;
            float rr = rl[i];
            float q2iv = q2i[i];
#pragma unroll
            for (int c = 0; c < 8; ++c) {
                float d = q2iv + q2j[tx * 8 + c] - 2.f * acc[r][c];
                float cv = sqrtf(fmaxf(d, 0.f) + 1e-12f);
                bool m = pi && (padj[tx * 8 + c] != 0);
                cp[c] += __expf(m ? fmaf(a, cv, bc) : 0.f) * rr;
            }
        }
#pragma unroll
        for (int c = 0; c < 8; ++c) {
            cp[c] += __shfl_xor(cp[c], 16);
            cp[c] += __shfl_xor(cp[c], 32);
        }
        if ((t & 48) == 0) {
#pragma unroll
            for (int c = 0; c < 8; ++c)
                csw[wv][(jt << 7) + tx * 8 + c] += cp[c];
        }
    }
    __syncthreads();
    for (int k = t; k < 512; k += 256) {
        float s = csw[0][k] + csw[1][k] + csw[2][k] + csw[3][k];
        atomicAdd(&colsum[(size_t)bh * NL + k], s);
    }
}

// ---------------- token-weight softmax w[b,l] ----------------
__global__ __launch_bounds__(512) void wk_kernel(
    const int* __restrict__ tids, const float* __restrict__ colsum, float* __restrict__ wvec) {
    __shared__ float red[8];
    __shared__ int redi[8];
    int b = blockIdx.x, l = threadIdx.x;
    int lane = l & 63, wv = l >> 6;
    int padv = (tids[(b << 9) + l] != 0) ? 1 : 0;
    int cnt = padv;
    for (int off = 1; off < 64; off <<= 1) cnt += __shfl_xor(cnt, off);
    if (lane == 0) redi[wv] = cnt;
    __syncthreads();
    int ds = 0;
    for (int k = 0; k < 8; ++k) ds += redi[k];
    if (ds < 1) ds = 1;
    float cs = 0.f;
    for (int hh = 0; hh < NH; ++hh) cs += colsum[(size_t)(b * NH + hh) * NL + l];
    float x = padv ? cs / (6.f * (float)ds) : -INFINITY;
    float m = x;
    for (int off = 1; off < 64; off <<= 1) m = fmaxf(m, __shfl_xor(m, off));
    if (lane == 0) red[wv] = m;
    __syncthreads();
    float bm = red[0];
    for (int k = 1; k < 8; ++k) bm = fmaxf(bm, red[k]);
    float e = padv ? __expf(x - bm) : 0.f;
    float se = e;
    for (int off = 1; off < 64; off <<= 1) se += __shfl_xor(se, off);
    __syncthreads();
    if (lane == 0) red[wv] = se;
    __syncthreads();
    float total = 0.f;
    for (int k = 0; k < 8; ++k) total += red[k];
    wvec[(b << 9) + l] = (total > 0.f) ? e / total : 0.f;
}

// ---------------- fc + per-token softmax + weighted sum ----------------
__global__ __launch_bounds__(256) void logits_kernel(
    const float* __restrict__ Vcat, const float* __restrict__ fcw, const float* __restrict__ fcb,
    const float* __restrict__ wvec, float* __restrict__ lacc) {
    __shared__ float red[4][64];
    int t = threadIdx.x;
    int wv = t >> 6, lane = t & 63;
    int tok0 = (blockIdx.x * 4 + wv) * 4;    // 16 consecutive tokens per block
    int b = tok0 >> 9;                       // all 16 in the same batch row
    int wrow = (lane < NCP) ? lane : (NCP - 1);
    const float* wp = fcw + wrow * ND;
    const float* vp = Vcat + (size_t)tok0 * ND;
    float acc0 = 0.f, acc1 = 0.f, acc2 = 0.f, acc3 = 0.f;
#pragma unroll 2
    for (int kc = 0; kc < ND; kc += 4) {
        float4 w4 = *(const float4*)(wp + kc);
        float4 v0 = *(const float4*)(vp + kc);
        float4 v1 = *(const float4*)(vp + ND + kc);
        float4 v2 = *(const float4*)(vp + 2 * ND + kc);
        float4 v3 = *(const float4*)(vp + 3 * ND + kc);
        acc0 += v0.x * w4.x + v0.y * w4.y + v0.z * w4.z + v0.w * w4.w;
        acc1 += v1.x * w4.x + v1.y * w4.y + v1.z * w4.z + v1.w * w4.w;
        acc2 += v2.x * w4.x + v2.y * w4.y + v2.z * w4.z + v2.w * w4.w;
        acc3 += v3.x * w4.x + v3.y * w4.y + v3.z * w4.z + v3.w * w4.w;
    }
    float bias = fcb[wrow];
    float g[4] = {acc0 + bias, acc1 + bias, acc2 + bias, acc3 + bias};
    float lsum = 0.f;
#pragma unroll
    for (int u = 0; u < 4; ++u) {
        float gm = (lane < NCP) ? g[u] : -INFINITY;
        float m = gm;
        for (int off = 1; off < 64; off <<= 1) m = fmaxf(m, __shfl_xor(m, off));
        float e = (lane < NCP) ? __expf(g[u] - m) : 0.f;
        float s = e;
        for (int off = 1; off < 64; off <<= 1) s += __shfl_xor(s, off);
        lsum += (e / s) * wvec[tok0 + u];
    }
    red[wv][lane] = lsum;
    __syncthreads();
    if (wv == 0) {
        float tot = red[0][lane] + red[1][lane] + red[2][lane] + red[3][lane];
        if (lane < NCP) atomicAdd(&lacc[b * NCP + lane], tot);
    }
}

// ---------------- final softmax over first 50 ----------------
__global__ __launch_bounds__(64) void final_kernel(const float* __restrict__ lacc, float* __restrict__ out) {
    int b = blockIdx.x, lane = threadIdx.x;
    float x = (lane < NC) ? lacc[b * NCP + lane] : -INFINITY;
    float m = x;
    for (int off = 1; off < 64; off <<= 1) m = fmaxf(m, __shfl_xor(m, off));
    float e = (lane < NC) ? __expf(x - m) : 0.f;
    float s = e;
    for (int off = 1; off < 64; off <<= 1) s += __shfl_xor(s, off);
    if (lane < NC) out[b * NC + lane] = e / s;
}

extern "C" void kernel_launch(void* const* d_in, const int* in_sizes, int n_in,
                              void* d_out, int out_size, void* d_ws, size_t ws_size,
                              hipStream_t stream) {
    const int* tids = (const int*)d_in[0];
    const int* TFs = (const int*)d_in[1];
    const int* DFs = (const int*)d_in[2];
    const float* emb = (const float*)d_in[3];
    const float* gamma = (const float*)d_in[4];
    const float* beta = (const float*)d_in[5];
    const float* fcw = (const float*)d_in[6];
    const float* fcb = (const float*)d_in[7];
    float* out = (float*)d_out;

    char* ws = (char*)d_ws;
    float* hw = (float*)ws;                              // 25,165,824 B
    float* q2 = (float*)(ws + 25165824);                 //    393,216 B
    float* Vcat = (float*)(ws + 25559040);               // 25,165,824 B
    float* rowinv = (float*)(ws + 50724864);             //    393,216 B
    char* zbase = ws + 51118080;                         //    400,000 B zero region
    double* stats = (double*)zbase;                      // 12 doubles (pad 128)
    float* colsum = (float*)(zbase + 128);               //    393,216 B
    float* lacc = (float*)(zbase + 128 + 393216);        //      6,656 B
    float* bnab = (float*)(ws + 51518080);               //         48 B
    float* wvec = (float*)(ws + 51518144);               //     65,536 B

    zero_kernel<<<64, 256, 0, stream>>>((float4*)zbase);
    embed_kernel<<<NB * NL, ND, 0, stream>>>(tids, TFs, DFs, emb, hw, q2);
    distA_kernel<<<NBH * 4, 256, 0, stream>>>(hw, q2, stats);
    fin_kernel<<<1, 64, 0, stream>>>(stats, gamma, beta, bnab);
    distPV_kernel<<<NBH * 8, 256, 0, stream>>>(hw, q2, tids, bnab, Vcat, rowinv);
    colsumC_kernel<<<NBH * 4, 256, 0, stream>>>(hw, q2, tids, bnab, rowinv, colsum);
    wk_kernel<<<NB, 512, 0, stream>>>(tids, colsum, wvec);
    logits_kernel<<<NB * 4, 256, 0, stream>>>(Vcat, fcw, fcb, wvec, lacc);
    final_kernel<<<NB, 64, 0, stream>>>(lacc, out);
}

// Round 11
// 345.357 us; speedup vs baseline: 2.3025x; 2.3025x over previous
//
#include <hip/hip_runtime.h>
#include <math.h>

#define NB 32
#define NL 512
#define ND 384
#define NH 6
#define NCP 52
#define NC 50
#define NBH (NB * NH)   // 192 head-batches
#define LDH 72          // padded u16 row stride for 64-wide bf16 LDS tiles

typedef __attribute__((ext_vector_type(8))) short bf16x8;
typedef __attribute__((ext_vector_type(4))) float f32x4;

__device__ __forceinline__ unsigned short f2bf(float x) {
    unsigned u = __float_as_uint(x);
    return (unsigned short)((u + 0x7FFFu + ((u >> 16) & 1u)) >> 16);
}
__device__ __forceinline__ float bf2f(unsigned short b) {
    return __uint_as_float(((unsigned)b) << 16);
}

// XCD-chunked decode, grid 1536: 8 XCDs x 192; consecutive sid share (b,h).
__device__ __forceinline__ void decode_blk(int orig, int& bh, int& i0) {
    int sid = (orig & 7) * 192 + (orig >> 3);
    i0 = (sid & 7) << 6;
    bh = sid >> 3;
}

// stage a 64x64 bf16 tile (global row stride grs u16) into padded LDS; 256 thr
__device__ __forceinline__ void stage_bf(const unsigned short* __restrict__ g,
                                         size_t grs, unsigned short* s, int t) {
#pragma unroll
    for (int it = 0; it < 2; ++it) {
        int e = t + (it << 8);
        int row = e >> 3, c8 = (e & 7) << 3;
        bf16x8 v = *(const bf16x8*)(g + (size_t)row * grs + c8);
        *(bf16x8*)(s + row * LDH + c8) = v;
    }
}

// ---------------- zero accumulators ----------------
__global__ void zero_kernel(float4* zb) {
    int idx = blockIdx.x * 256 + threadIdx.x;
    float4 z; z.x = 0.f; z.y = 0.f; z.z = 0.f; z.w = 0.f;
    for (int i = idx; i < 25000; i += 64 * 256) zb[i] = z;
}

// ---------------- embedding + tfidf weight + q2 ----------------
__global__ __launch_bounds__(384) void embed_kernel(
    const int* __restrict__ tids, const int* __restrict__ TFs, const int* __restrict__ DFs,
    const float* __restrict__ emb, float* __restrict__ hw, float* __restrict__ q2) {
    int t = threadIdx.x;
    int bl = blockIdx.x;               // 0..B*L-1
    int b = bl >> 9, l = bl & 511;
    int tid = tids[bl];
    float tf = log1pf(fminf((float)TFs[bl], 20.f));
    float idf = 1.f / logf((float)DFs[bl] + 2.f);
    float wt = tf * idf;
    float hv = emb[(size_t)tid * ND + t] * wt;
    int hh = t >> 6, dd = t & 63;
    hw[((size_t)(b * NH + hh) * NL + l) * 64 + dd] = hv;
    float q = hv * hv;
    for (int off = 1; off < 64; off <<= 1) q += __shfl_xor(q, off);
    if (dd == 0) q2[(b * NH + hh) * NL + l] = q;
}

// ---------------- split f32 -> bf16 hi/lo, row-major + transposed ----------------
__global__ __launch_bounds__(256) void tr_kernel(
    const float* __restrict__ hw,
    unsigned short* __restrict__ Hhi, unsigned short* __restrict__ Hlo,
    unsigned short* __restrict__ Thi, unsigned short* __restrict__ Tlo) {
    __shared__ float tile[64][65];
    int t = threadIdx.x;
    int bh = blockIdx.x >> 3, l0 = (blockIdx.x & 7) << 6;
    const float* src = hw + ((size_t)bh * NL + l0) * 64;
#pragma unroll
    for (int it = 0; it < 4; ++it) {
        int e = t + (it << 8);
        int row = e >> 4, c4 = (e & 15) << 2;
        float4 v = *(const float4*)(src + (size_t)row * 64 + c4);
        tile[row][c4] = v.x; tile[row][c4 + 1] = v.y;
        tile[row][c4 + 2] = v.z; tile[row][c4 + 3] = v.w;
        ushort4 h, lo;
        h.x = f2bf(v.x); lo.x = f2bf(v.x - bf2f(h.x));
        h.y = f2bf(v.y); lo.y = f2bf(v.y - bf2f(h.y));
        h.z = f2bf(v.z); lo.z = f2bf(v.z - bf2f(h.z));
        h.w = f2bf(v.w); lo.w = f2bf(v.w - bf2f(h.w));
        size_t off = ((size_t)bh * NL + l0 + row) * 64 + c4;
        *(ushort4*)(Hhi + off) = h;
        *(ushort4*)(Hlo + off) = lo;
    }
    __syncthreads();
    int d = t >> 2, lc0 = (t & 3) << 4;
    unsigned short hh[16], ll[16];
#pragma unroll
    for (int k = 0; k < 16; ++k) {
        float v = tile[lc0 + k][d];
        unsigned short hv = f2bf(v);
        hh[k] = hv; ll[k] = f2bf(v - bf2f(hv));
    }
    size_t toff = ((size_t)bh * 64 + d) * NL + l0 + lc0;
#pragma unroll
    for (int k = 0; k < 4; ++k) {
        ushort4 a, c;
        a.x = hh[4 * k]; a.y = hh[4 * k + 1]; a.z = hh[4 * k + 2]; a.w = hh[4 * k + 3];
        c.x = ll[4 * k]; c.y = ll[4 * k + 1]; c.z = ll[4 * k + 2]; c.w = ll[4 * k + 3];
        *(ushort4*)(Thi + toff + 4 * k) = a;
        *(ushort4*)(Tlo + toff + 4 * k) = c;
    }
}

// ---------------- pass A: MFMA dist -> BN stats ----------------
__global__ __launch_bounds__(256, 2) void distA_kernel(
    const unsigned short* __restrict__ gHhi, const unsigned short* __restrict__ gHlo,
    const float* __restrict__ q2g, double* __restrict__ stats) {
    __shared__ unsigned short sHhi[64 * LDH], sHlo[64 * LDH];
    __shared__ float q2j_s[NL];
    __shared__ float q2i_s[64];
    __shared__ float red[8];
    int t = threadIdx.x;
    int lane = t & 63, ws = t >> 6;
    int bh, i0; decode_blk(blockIdx.x, bh, i0);
    for (int k = t; k < NL; k += 256) q2j_s[k] = q2g[(size_t)bh * NL + k];
    if (t < 64) q2i_s[t] = q2g[(size_t)bh * NL + i0 + t];
    int irow = i0 + (ws << 4) + (lane & 15);
    int koff = (lane >> 4) << 3;
    const unsigned short* ahb = gHhi + ((size_t)bh * NL + irow) * 64;
    const unsigned short* alb = gHlo + ((size_t)bh * NL + irow) * 64;
    bf16x8 Ahi[2], Alo[2];
    Ahi[0] = *(const bf16x8*)(ahb + koff);
    Ahi[1] = *(const bf16x8*)(ahb + koff + 32);
    Alo[0] = *(const bf16x8*)(alb + koff);
    Alo[1] = *(const bf16x8*)(alb + koff + 32);
    __syncthreads();
    int drb = (lane >> 4) << 2, col = lane & 15;
    float q2i_r[4];
#pragma unroll
    for (int r = 0; r < 4; ++r) q2i_r[r] = q2i_s[(ws << 4) + drb + r];
    float lsum = 0.f, lss = 0.f;
    for (int jc = 0; jc < 8; ++jc) {
        if (jc) __syncthreads();
        int j0 = jc << 6;
        stage_bf(gHhi + ((size_t)bh * NL + j0) * 64, 64, sHhi, t);
        stage_bf(gHlo + ((size_t)bh * NL + j0) * 64, 64, sHlo, t);
        __syncthreads();
#pragma unroll
        for (int jt = 0; jt < 4; ++jt) {
            f32x4 acc = {0.f, 0.f, 0.f, 0.f};
            int brow = (jt << 4) + col;
#pragma unroll
            for (int kc = 0; kc < 2; ++kc) {
                bf16x8 bhi = *(const bf16x8*)(sHhi + brow * LDH + koff + (kc << 5));
                bf16x8 blo = *(const bf16x8*)(sHlo + brow * LDH + koff + (kc << 5));
                acc = __builtin_amdgcn_mfma_f32_16x16x32_bf16(Ahi[kc], bhi, acc, 0, 0, 0);
                acc = __builtin_amdgcn_mfma_f32_16x16x32_bf16(Ahi[kc], blo, acc, 0, 0, 0);
                acc = __builtin_amdgcn_mfma_f32_16x16x32_bf16(Alo[kc], bhi, acc, 0, 0, 0);
            }
            float q2jv = q2j_s[j0 + (jt << 4) + col];
#pragma unroll
            for (int r = 0; r < 4; ++r) {
                float d2 = q2i_r[r] + q2jv - 2.f * acc[r];
                float dd = sqrtf(fmaxf(d2, 0.f) + 1e-12f);
                lsum += dd;
                lss += dd * dd;
            }
        }
    }
    for (int off = 1; off < 64; off <<= 1) {
        lsum += __shfl_xor(lsum, off);
        lss += __shfl_xor(lss, off);
    }
    __syncthreads();
    if (lane == 0) { red[ws * 2] = lsum; red[ws * 2 + 1] = lss; }
    __syncthreads();
    if (t == 0) {
        float s = 0.f, ss = 0.f;
        for (int w = 0; w < 4; ++w) { s += red[w * 2]; ss += red[w * 2 + 1]; }
        int h = bh % NH;
        atomicAdd(&stats[h * 2], (double)s);
        atomicAdd(&stats[h * 2 + 1], (double)ss);
    }
}

// ---------------- finalize BN affine for all heads ----------------
__global__ void fin_kernel(const double* __restrict__ stats, const float* __restrict__ gamma,
                           const float* __restrict__ beta, float* __restrict__ bnab) {
    int h = threadIdx.x;
    if (h < NH) {
        double n = (double)NB * NL * NL;
        double mu = stats[h * 2] / n;
        double var = stats[h * 2 + 1] / n - mu * mu;
        double inv = 1.0 / sqrt(var + 1e-5);
        double a = (double)gamma[h] * inv;
        bnab[h * 2] = (float)a;
        bnab[h * 2 + 1] = (float)((double)beta[h] - mu * a);
    }
}

// ---------------- pass B: MFMA dist + exp -> MFMA PV + rowinv ----------------
__global__ __launch_bounds__(256, 2) void distB_kernel(
    const unsigned short* __restrict__ gHhi, const unsigned short* __restrict__ gHlo,
    const unsigned short* __restrict__ gThi, const unsigned short* __restrict__ gTlo,
    const float* __restrict__ q2g, const int* __restrict__ tids,
    const float* __restrict__ bnab, float* __restrict__ Vcat, float* __restrict__ rowinv) {
    __shared__ unsigned short sHhi[64 * LDH], sHlo[64 * LDH];
    __shared__ unsigned short sThi[64 * LDH], sTlo[64 * LDH];
    __shared__ unsigned short sPhi[4][16 * LDH], sPlo[4][16 * LDH];
    __shared__ float q2j_s[NL];
    __shared__ int padj_s[NL];
    __shared__ float q2i_s[64];
    __shared__ int padi_s[64];
    int t = threadIdx.x;
    int lane = t & 63, ws = t >> 6;
    int bh, i0; decode_blk(blockIdx.x, bh, i0);
    int b = bh / NH, h = bh % NH;
    float aa = bnab[h * 2], bc = bnab[h * 2 + 1];
    for (int k = t; k < NL; k += 256) {
        q2j_s[k] = q2g[(size_t)bh * NL + k];
        padj_s[k] = (tids[(b << 9) + k] != 0) ? 1 : 0;
    }
    if (t < 64) {
        q2i_s[t] = q2g[(size_t)bh * NL + i0 + t];
        padi_s[t] = (tids[(b << 9) + i0 + t] != 0) ? 1 : 0;
    }
    int irow = i0 + (ws << 4) + (lane & 15);
    int koff = (lane >> 4) << 3;
    const unsigned short* ahb = gHhi + ((size_t)bh * NL + irow) * 64;
    const unsigned short* alb = gHlo + ((size_t)bh * NL + irow) * 64;
    bf16x8 Ahi[2], Alo[2];
    Ahi[0] = *(const bf16x8*)(ahb + koff);
    Ahi[1] = *(const bf16x8*)(ahb + koff + 32);
    Alo[0] = *(const bf16x8*)(alb + koff);
    Alo[1] = *(const bf16x8*)(alb + koff + 32);
    __syncthreads();
    int drb = (lane >> 4) << 2, col = lane & 15;
    float q2i_r[4]; bool pi_r[4];
#pragma unroll
    for (int r = 0; r < 4; ++r) {
        q2i_r[r] = q2i_s[(ws << 4) + drb + r];
        pi_r[r] = padi_s[(ws << 4) + drb + r] != 0;
    }
    f32x4 zv = {0.f, 0.f, 0.f, 0.f};
    f32x4 U[4] = {zv, zv, zv, zv};
    float racc[4] = {0.f, 0.f, 0.f, 0.f};
    unsigned short* Pw_hi = sPhi[ws];
    unsigned short* Pw_lo = sPlo[ws];
    for (int jc = 0; jc < 8; ++jc) {
        if (jc) __syncthreads();
        int j0 = jc << 6;
        stage_bf(gHhi + ((size_t)bh * NL + j0) * 64, 64, sHhi, t);
        stage_bf(gHlo + ((size_t)bh * NL + j0) * 64, 64, sHlo, t);
        stage_bf(gThi + (size_t)bh * 64 * NL + j0, NL, sThi, t);
        stage_bf(gTlo + (size_t)bh * 64 * NL + j0, NL, sTlo, t);
        __syncthreads();
        // QK^T (split-bf16) -> d -> exp -> P (hi/lo) into per-wave LDS
#pragma unroll
        for (int jt = 0; jt < 4; ++jt) {
            f32x4 acc = {0.f, 0.f, 0.f, 0.f};
            int brow = (jt << 4) + col;
#pragma unroll
            for (int kc = 0; kc < 2; ++kc) {
                bf16x8 bhi = *(const bf16x8*)(sHhi + brow * LDH + koff + (kc << 5));
                bf16x8 blo = *(const bf16x8*)(sHlo + brow * LDH + koff + (kc << 5));
                acc = __builtin_amdgcn_mfma_f32_16x16x32_bf16(Ahi[kc], bhi, acc, 0, 0, 0);
                acc = __builtin_amdgcn_mfma_f32_16x16x32_bf16(Ahi[kc], blo, acc, 0, 0, 0);
                acc = __builtin_amdgcn_mfma_f32_16x16x32_bf16(Alo[kc], bhi, acc, 0, 0, 0);
            }
            float q2jv = q2j_s[j0 + (jt << 4) + col];
            bool pj = padj_s[j0 + (jt << 4) + col] != 0;
#pragma unroll
            for (int r = 0; r < 4; ++r) {
                float d2 = q2i_r[r] + q2jv - 2.f * acc[r];
                float dd = sqrtf(fmaxf(d2, 0.f) + 1e-12f);
                float z = (pi_r[r] && pj) ? fmaf(aa, dd, bc) : 0.f;
                float e = __expf(z);
                racc[r] += e;
                unsigned short hi = f2bf(e);
                unsigned short lo = f2bf(e - bf2f(hi));
                Pw_hi[(drb + r) * LDH + (jt << 4) + col] = hi;
                Pw_lo[(drb + r) * LDH + (jt << 4) + col] = lo;
            }
        }
        // PV (split-bf16), per-wave P buffer (within-wave dependency)
#pragma unroll
        for (int kc = 0; kc < 2; ++kc) {
            bf16x8 pah = *(const bf16x8*)(Pw_hi + col * LDH + koff + (kc << 5));
            bf16x8 pal = *(const bf16x8*)(Pw_lo + col * LDH + koff + (kc << 5));
#pragma unroll
            for (int dt = 0; dt < 4; ++dt) {
                int vrow = (dt << 4) + col;
                bf16x8 vhi = *(const bf16x8*)(sThi + vrow * LDH + koff + (kc << 5));
                bf16x8 vlo = *(const bf16x8*)(sTlo + vrow * LDH + koff + (kc << 5));
                U[dt] = __builtin_amdgcn_mfma_f32_16x16x32_bf16(pah, vhi, U[dt], 0, 0, 0);
                U[dt] = __builtin_amdgcn_mfma_f32_16x16x32_bf16(pah, vlo, U[dt], 0, 0, 0);
                U[dt] = __builtin_amdgcn_mfma_f32_16x16x32_bf16(pal, vhi, U[dt], 0, 0, 0);
            }
        }
    }
    // row sums -> inverse (reduce over the 16 col-lanes)
    float riv[4];
#pragma unroll
    for (int r = 0; r < 4; ++r) {
        float s = racc[r];
        s += __shfl_xor(s, 1); s += __shfl_xor(s, 2);
        s += __shfl_xor(s, 4); s += __shfl_xor(s, 8);
        riv[r] = 1.f / s;
    }
    if (col == 0) {
#pragma unroll
        for (int r = 0; r < 4; ++r)
            rowinv[(size_t)bh * NL + i0 + (ws << 4) + drb + r] = riv[r];
    }
#pragma unroll
    for (int dt = 0; dt < 4; ++dt)
#pragma unroll
        for (int r = 0; r < 4; ++r) {
            int row = i0 + (ws << 4) + drb + r;
            Vcat[((size_t)(b << 9) + row) * ND + h * 64 + (dt << 4) + col] = U[dt][r] * riv[r];
        }
}

// ---------------- pass C: MFMA dist + exp*(1/l) -> colsum ----------------
__global__ __launch_bounds__(256, 2) void distC_kernel(
    const unsigned short* __restrict__ gHhi, const unsigned short* __restrict__ gHlo,
    const float* __restrict__ q2g, const int* __restrict__ tids,
    const float* __restrict__ bnab, const float* __restrict__ rowinv,
    float* __restrict__ colsum) {
    __shared__ unsigned short sHhi[64 * LDH], sHlo[64 * LDH];
    __shared__ float q2j_s[NL];
    __shared__ int padj_s[NL];
    __shared__ float q2i_s[64], riv_s[64];
    __shared__ int padi_s[64];
    __shared__ float csw[4][NL];
    int t = threadIdx.x;
    int lane = t & 63, ws = t >> 6;
    int bh, i0; decode_blk(blockIdx.x, bh, i0);
    int b = bh / NH, h = bh % NH;
    float aa = bnab[h * 2], bc = bnab[h * 2 + 1];
    for (int k = t; k < NL; k += 256) {
        q2j_s[k] = q2g[(size_t)bh * NL + k];
        padj_s[k] = (tids[(b << 9) + k] != 0) ? 1 : 0;
    }
    if (t < 64) {
        q2i_s[t] = q2g[(size_t)bh * NL + i0 + t];
        padi_s[t] = (tids[(b << 9) + i0 + t] != 0) ? 1 : 0;
        riv_s[t] = rowinv[(size_t)bh * NL + i0 + t];
    }
    for (int k = t; k < 4 * NL; k += 256) ((float*)csw)[k] = 0.f;
    int irow = i0 + (ws << 4) + (lane & 15);
    int koff = (lane >> 4) << 3;
    const unsigned short* ahb = gHhi + ((size_t)bh * NL + irow) * 64;
    const unsigned short* alb = gHlo + ((size_t)bh * NL + irow) * 64;
    bf16x8 Ahi[2], Alo[2];
    Ahi[0] = *(const bf16x8*)(ahb + koff);
    Ahi[1] = *(const bf16x8*)(ahb + koff + 32);
    Alo[0] = *(const bf16x8*)(alb + koff);
    Alo[1] = *(const bf16x8*)(alb + koff + 32);
    __syncthreads();
    int drb = (lane >> 4) << 2, col = lane & 15;
    float q2i_r[4], riv_r[4]; bool pi_r[4];
#pragma unroll
    for (int r = 0; r < 4; ++r) {
        q2i_r[r] = q2i_s[(ws << 4) + drb + r];
        pi_r[r] = padi_s[(ws << 4) + drb + r] != 0;
        riv_r[r] = riv_s[(ws << 4) + drb + r];
    }
    for (int jc = 0; jc < 8; ++jc) {
        if (jc) __syncthreads();
        int j0 = jc << 6;
        stage_bf(gHhi + ((size_t)bh * NL + j0) * 64, 64, sHhi, t);
        stage_bf(gHlo + ((size_t)bh * NL + j0) * 64, 64, sHlo, t);
        __syncthreads();
#pragma unroll
        for (int jt = 0; jt < 4; ++jt) {
            f32x4 acc = {0.f, 0.f, 0.f, 0.f};
            int brow = (jt << 4) + col;
#pragma unroll
            for (int kc = 0; kc < 2; ++kc) {
                bf16x8 bhi = *(const bf16x8*)(sHhi + brow * LDH + koff + (kc << 5));
                bf16x8 blo = *(const bf16x8*)(sHlo + brow * LDH + koff + (kc << 5));
                acc = __builtin_amdgcn_mfma_f32_16x16x32_bf16(Ahi[kc], bhi, acc, 0, 0, 0);
                acc = __builtin_amdgcn_mfma_f32_16x16x32_bf16(Ahi[kc], blo, acc, 0, 0, 0);
                acc = __builtin_amdgcn_mfma_f32_16x16x32_bf16(Alo[kc], bhi, acc, 0, 0, 0);
            }
            float q2jv = q2j_s[j0 + (jt << 4) + col];
            bool pj = padj_s[j0 + (jt << 4) + col] != 0;
            float cp = 0.f;
#pragma unroll
            for (int r = 0; r < 4; ++r) {
                float d2 = q2i_r[r] + q2jv - 2.f * acc[r];
                float dd = sqrtf(fmaxf(d2, 0.f) + 1e-12f);
                float z = (pi_r[r] && pj) ? fmaf(aa, dd, bc) : 0.f;
                cp += __expf(z) * riv_r[r];
            }
            cp += __shfl_xor(cp, 16);
            cp += __shfl_xor(cp, 32);
            if (lane < 16) csw[ws][j0 + (jt << 4) + lane] += cp;
        }
    }
    __syncthreads();
    for (int k = t; k < NL; k += 256) {
        float s = csw[0][k] + csw[1][k] + csw[2][k] + csw[3][k];
        atomicAdd(&colsum[(size_t)bh * NL + k], s);
    }
}

// ---------------- token-weight softmax w[b,l] ----------------
__global__ __launch_bounds__(512) void wk_kernel(
    const int* __restrict__ tids, const float* __restrict__ colsum, float* __restrict__ wvec) {
    __shared__ float red[8];
    __shared__ int redi[8];
    int b = blockIdx.x, l = threadIdx.x;
    int lane = l & 63, wv = l >> 6;
    int padv = (tids[(b << 9) + l] != 0) ? 1 : 0;
    int cnt = padv;
    for (int off = 1; off < 64; off <<= 1) cnt += __shfl_xor(cnt, off);
    if (lane == 0) redi[wv] = cnt;
    __syncthreads();
    int ds = 0;
    for (int k = 0; k < 8; ++k) ds += redi[k];
    if (ds < 1) ds = 1;
    float cs = 0.f;
    for (int hh = 0; hh < NH; ++hh) cs += colsum[(size_t)(b * NH + hh) * NL + l];
    float x = padv ? cs / (6.f * (float)ds) : -INFINITY;
    float m = x;
    for (int off = 1; off < 64; off <<= 1) m = fmaxf(m, __shfl_xor(m, off));
    if (lane == 0) red[wv] = m;
    __syncthreads();
    float bm = red[0];
    for (int k = 1; k < 8; ++k) bm = fmaxf(bm, red[k]);
    float e = padv ? __expf(x - bm) : 0.f;
    float se = e;
    for (int off = 1; off < 64; off <<= 1) se += __shfl_xor(se, off);
    __syncthreads();
    if (lane == 0) red[wv] = se;
    __syncthreads();
    float total = 0.f;
    for (int k = 0; k < 8; ++k) total += red[k];
    wvec[(b << 9) + l] = (total > 0.f) ? e / total : 0.f;
}

// ---------------- fc + per-token softmax + weighted sum ----------------
__global__ __launch_bounds__(256) void logits_kernel(
    const float* __restrict__ Vcat, const float* __restrict__ fcw, const float* __restrict__ fcb,
    const float* __restrict__ wvec, float* __restrict__ lacc) {
    __shared__ float red[4][64];
    int t = threadIdx.x;
    int wv = t >> 6, lane = t & 63;
    int tok0 = (blockIdx.x * 4 + wv) * 4;
    int b = tok0 >> 9;
    int wrow = (lane < NCP) ? lane : (NCP - 1);
    const float* wp = fcw + wrow * ND;
    const float* vp = Vcat + (size_t)tok0 * ND;
    float acc0 = 0.f, acc1 = 0.f, acc2 = 0.f, acc3 = 0.f;
#pragma unroll 2
    for (int kc = 0; kc < ND; kc += 4) {
        float4 w4 = *(const float4*)(wp + kc);
        float4 v0 = *(const float4*)(vp + kc);
        float4 v1 = *(const float4*)(vp + ND + kc);
        float4 v2 = *(const float4*)(vp + 2 * ND + kc);
        float4 v3 = *(const float4*)(vp + 3 * ND + kc);
        acc0 += v0.x * w4.x + v0.y * w4.y + v0.z * w4.z + v0.w * w4.w;
        acc1 += v1.x * w4.x + v1.y * w4.y + v1.z * w4.z + v1.w * w4.w;
        acc2 += v2.x * w4.x + v2.y * w4.y + v2.z * w4.z + v2.w * w4.w;
        acc3 += v3.x * w4.x + v3.y * w4.y + v3.z * w4.z + v3.w * w4.w;
    }
    float bias = fcb[wrow];
    float g[4] = {acc0 + bias, acc1 + bias, acc2 + bias, acc3 + bias};
    float lsum = 0.f;
#pragma unroll
    for (int u = 0; u < 4; ++u) {
        float gm = (lane < NCP) ? g[u] : -INFINITY;
        float m = gm;
        for (int off = 1; off < 64; off <<= 1) m = fmaxf(m, __shfl_xor(m, off));
        float e = (lane < NCP) ? __expf(g[u] - m) : 0.f;
        float s = e;
        for (int off = 1; off < 64; off <<= 1) s += __shfl_xor(s, off);
        lsum += (e / s) * wvec[tok0 + u];
    }
    red[wv][lane] = lsum;
    __syncthreads();
    if (wv == 0) {
        float tot = red[0][lane] + red[1][lane] + red[2][lane] + red[3][lane];
        if (lane < NCP) atomicAdd(&lacc[b * NCP + lane], tot);
    }
}

// ---------------- final softmax over first 50 ----------------
__global__ __launch_bounds__(64) void final_kernel(const float* __restrict__ lacc, float* __restrict__ out) {
    int b = blockIdx.x, lane = threadIdx.x;
    float x = (lane < NC) ? lacc[b * NCP + lane] : -INFINITY;
    float m = x;
    for (int off = 1; off < 64; off <<= 1) m = fmaxf(m, __shfl_xor(m, off));
    float e = (lane < NC) ? __expf(x - m) : 0.f;
    float s = e;
    for (int off = 1; off < 64; off <<= 1) s += __shfl_xor(s, off);
    if (lane < NC) out[b * NC + lane] = e / s;
}

extern "C" void kernel_launch(void* const* d_in, const int* in_sizes, int n_in,
                              void* d_out, int out_size, void* d_ws, size_t ws_size,
                              hipStream_t stream) {
    const int* tids = (const int*)d_in[0];
    const int* TFs = (const int*)d_in[1];
    const int* DFs = (const int*)d_in[2];
    const float* emb = (const float*)d_in[3];
    const float* gamma = (const float*)d_in[4];
    const float* beta = (const float*)d_in[5];
    const float* fcw = (const float*)d_in[6];
    const float* fcb = (const float*)d_in[7];
    float* out = (float*)d_out;

    char* ws = (char*)d_ws;
    float* hw = (float*)ws;                                  // 25,165,824 B (dead after tr)
    float* Vcat = (float*)ws;                                // aliases hw (written in pass B)
    float* q2 = (float*)(ws + 25165824);                     //    393,216 B
    unsigned short* Hhi = (unsigned short*)(ws + 25559040);  // 12,582,912 B
    unsigned short* Hlo = (unsigned short*)(ws + 38141952);  // 12,582,912 B
    unsigned short* Thi = (unsigned short*)(ws + 50724864);  // 12,582,912 B
    unsigned short* Tlo = (unsigned short*)(ws + 63307776);  // 12,582,912 B
    float* rowinv = (float*)(ws + 75890688);                 //    393,216 B
    char* zbase = ws + 76283904;                             //    400,000 B zero region
    double* stats = (double*)zbase;                          // 12 doubles (pad 128)
    float* colsum = (float*)(zbase + 128);                   //    393,216 B
    float* lacc = (float*)(zbase + 128 + 393216);            //      6,656 B
    float* bnab = (float*)(ws + 76683904);                   //         48 B
    float* wvec = (float*)(ws + 76684032);                   //     65,536 B

    zero_kernel<<<64, 256, 0, stream>>>((float4*)zbase);
    embed_kernel<<<NB * NL, ND, 0, stream>>>(tids, TFs, DFs, emb, hw, q2);
    tr_kernel<<<NBH * 8, 256, 0, stream>>>(hw, Hhi, Hlo, Thi, Tlo);
    distA_kernel<<<NBH * 8, 256, 0, stream>>>(Hhi, Hlo, q2, stats);
    fin_kernel<<<1, 64, 0, stream>>>(stats, gamma, beta, bnab);
    distB_kernel<<<NBH * 8, 256, 0, stream>>>(Hhi, Hlo, Thi, Tlo, q2, tids, bnab, Vcat, rowinv);
    distC_kernel<<<NBH * 8, 256, 0, stream>>>(Hhi, Hlo, q2, tids, bnab, rowinv, colsum);
    wk_kernel<<<NB, 512, 0, stream>>>(tids, colsum, wvec);
    logits_kernel<<<NB * 4, 256, 0, stream>>>(Vcat, fcw, fcb, wvec, lacc);
    final_kernel<<<NB, 64, 0, stream>>>(lacc, out);
}